// Round 1
// baseline (2930.793 us; speedup 1.0000x reference)
//
#include <hip/hip_runtime.h>

using u16 = unsigned short;
using u32 = unsigned int;

typedef __bf16 bf16x8 __attribute__((ext_vector_type(8)));
typedef float f32x4 __attribute__((ext_vector_type(4)));

__device__ __forceinline__ u16 f2bf(float f) {
  u32 u = __builtin_bit_cast(u32, f);
  u = u + 0x7FFFu + ((u >> 16) & 1u);  // round-to-nearest-even
  return (u16)(u >> 16);
}
__device__ __forceinline__ float bf2f(u16 h) {
  return __builtin_bit_cast(float, (u32)h << 16);
}

// ------------------------------------------------------------------
// transpose + f32->bf16 convert:  out[c][r] = bf16(in[r][c]) per layer z
// R,C multiples of 32.
// ------------------------------------------------------------------
__global__ __launch_bounds__(256) void transpose_f32_bf16(
    const float* __restrict__ in, u16* __restrict__ out, int R, int C) {
  __shared__ u16 tile[32][33];
  long zofs = (long)blockIdx.z * R * C;
  int c0 = blockIdx.x * 32, r0 = blockIdx.y * 32;
  for (int i = threadIdx.y; i < 32; i += 8)
    tile[i][threadIdx.x] = f2bf(in[zofs + (long)(r0 + i) * C + c0 + threadIdx.x]);
  __syncthreads();
  for (int i = threadIdx.y; i < 32; i += 8)
    out[zofs + (long)(c0 + i) * R + r0 + threadIdx.x] = tile[threadIdx.x][i];
}

// bf16 strided transpose: out[c][r] = in[r*ldin + c]   (R rows, C cols of in)
__global__ __launch_bounds__(256) void transpose_bf16(
    const u16* __restrict__ in, int ldin, u16* __restrict__ out, int R, int C) {
  __shared__ u16 tile[32][33];
  int c0 = blockIdx.x * 32, r0 = blockIdx.y * 32;
  for (int i = threadIdx.y; i < 32; i += 8)
    tile[i][threadIdx.x] = in[(long)(r0 + i) * ldin + c0 + threadIdx.x];
  __syncthreads();
  for (int i = threadIdx.y; i < 32; i += 8)
    out[(long)(c0 + i) * R + r0 + threadIdx.x] = tile[threadIdx.x][i];
}

// ------------------------------------------------------------------
// General bf16 GEMM, B transposed:  C[m][n] = sum_k A[m][k] * BT[n][k]
// 128x128 tile, BK=32, 4 waves, each wave 4x4 frags of mfma 16x16x32 bf16.
// Epilogue: *scale + bias[n]; optional fp32 accumulate (residual stream),
// optional ReLU + bf16 store. Batched over blockIdx.z via element strides.
// ------------------------------------------------------------------
constexpr int BM = 128, BN = 128, BK = 32, LDSP = 40;  // +8 bf16 pad per row

__global__ __launch_bounds__(256) void gemm_bt(
    const u16* __restrict__ A, int lda, long aBatch,
    const u16* __restrict__ B, int ldb, long bBatch,
    const float* __restrict__ bias,
    u16* __restrict__ outBf, long obBatch, int ldob,
    float* __restrict__ outF, long ofBatch, int ldof, int accF,
    int M, int N, int K, float scale, int relu) {
  __shared__ u16 As[BM * LDSP];
  __shared__ u16 Bs[BN * LDSP];
  const int bz = blockIdx.z;
  A += (long)bz * aBatch;
  B += (long)bz * bBatch;
  const int m0 = blockIdx.y * BM, n0 = blockIdx.x * BN;
  const int tid = threadIdx.x, lane = tid & 63, wid = tid >> 6;
  const int wr = (wid >> 1) * 64, wc = (wid & 1) * 64;
  const int r16 = lane & 15, kg8 = (lane >> 4) * 8;

  f32x4 acc[4][4];
#pragma unroll
  for (int i = 0; i < 4; ++i)
#pragma unroll
    for (int j = 0; j < 4; ++j) acc[i][j] = f32x4{0.f, 0.f, 0.f, 0.f};

  const int nkt = K / BK;
  for (int kt = 0; kt < nkt; ++kt) {
    const int k0 = kt * BK;
    __syncthreads();
    // stage A and B tiles: 128 rows x 32 bf16, 16B chunks, 2 chunks/thread each
#pragma unroll
    for (int c = 0; c < 2; ++c) {
      int idx = tid + c * 256;
      int row = idx >> 2, kc = (idx & 3) * 8;
      uint4 va = make_uint4(0u, 0u, 0u, 0u);
      int gm = m0 + row;
      if (gm < M) va = *reinterpret_cast<const uint4*>(A + (long)gm * lda + k0 + kc);
      *reinterpret_cast<uint4*>(&As[row * LDSP + kc]) = va;
      uint4 vb = make_uint4(0u, 0u, 0u, 0u);
      int gn = n0 + row;
      if (gn < N) vb = *reinterpret_cast<const uint4*>(B + (long)gn * ldb + k0 + kc);
      *reinterpret_cast<uint4*>(&Bs[row * LDSP + kc]) = vb;
    }
    __syncthreads();

    bf16x8 af[4], bfv[4];
#pragma unroll
    for (int i = 0; i < 4; ++i)
      af[i] = *reinterpret_cast<const bf16x8*>(&As[(wr + i * 16 + r16) * LDSP + kg8]);
#pragma unroll
    for (int j = 0; j < 4; ++j)
      bfv[j] = *reinterpret_cast<const bf16x8*>(&Bs[(wc + j * 16 + r16) * LDSP + kg8]);
#pragma unroll
    for (int i = 0; i < 4; ++i)
#pragma unroll
      for (int j = 0; j < 4; ++j)
        acc[i][j] = __builtin_amdgcn_mfma_f32_16x16x32_bf16(af[i], bfv[j], acc[i][j], 0, 0, 0);
  }

  // epilogue: C/D frag layout (verified): col = lane&15, row = (lane>>4)*4 + r
  const int rg = (lane >> 4) * 4;
#pragma unroll
  for (int i = 0; i < 4; ++i) {
#pragma unroll
    for (int j = 0; j < 4; ++j) {
      int col = n0 + wc + j * 16 + r16;
      if (col >= N) continue;
      float bv = bias ? bias[col] : 0.f;
#pragma unroll
      for (int r = 0; r < 4; ++r) {
        int row = m0 + wr + i * 16 + rg + r;
        if (row >= M) continue;
        float v = acc[i][j][r] * scale + bv;
        if (outF) {
          long idx = (long)bz * ofBatch + (long)row * ldof + col;
          if (accF) outF[idx] += v;
          else outF[idx] = v;
        }
        if (outBf) {
          if (relu && v < 0.f) v = 0.f;
          outBf[(long)bz * obBatch + (long)row * ldob + col] = f2bf(v);
        }
      }
    }
  }
}

// ------------------------------------------------------------------
// LayerNorm over D=512, one block (256 thr) per row. OUTBF: bf16 vs f32 out.
// ------------------------------------------------------------------
__device__ __forceinline__ void block_reduce2(float& s, float& ss) {
#pragma unroll
  for (int o = 32; o; o >>= 1) {
    s += __shfl_xor(s, o);
    ss += __shfl_xor(ss, o);
  }
  __shared__ float sm[8];
  int wid = threadIdx.x >> 6;
  if ((threadIdx.x & 63) == 0) {
    sm[wid] = s;
    sm[wid + 4] = ss;
  }
  __syncthreads();
  s = sm[0] + sm[1] + sm[2] + sm[3];
  ss = sm[4] + sm[5] + sm[6] + sm[7];
}

template <int OUTBF>
__global__ __launch_bounds__(256) void layernorm_k(
    const float* __restrict__ xin, const float* __restrict__ g,
    const float* __restrict__ bta, void* __restrict__ out) {
  const int row = blockIdx.x, tid = threadIdx.x;
  const float2 v = *reinterpret_cast<const float2*>(xin + (long)row * 512 + tid * 2);
  float s = v.x + v.y, ss = v.x * v.x + v.y * v.y;
  block_reduce2(s, ss);
  const float mean = s * (1.f / 512.f);
  const float var = ss * (1.f / 512.f) - mean * mean;
  const float inv = rsqrtf(var + 1e-5f);
  const float2 gg = *reinterpret_cast<const float2*>(g + tid * 2);
  const float2 bb = *reinterpret_cast<const float2*>(bta + tid * 2);
  const float y0 = (v.x - mean) * inv * gg.x + bb.x;
  const float y1 = (v.y - mean) * inv * gg.y + bb.y;
  if (OUTBF) {
    u16* o = (u16*)out + (long)row * 512 + tid * 2;
    o[0] = f2bf(y0);
    o[1] = f2bf(y1);
  } else {
    *reinterpret_cast<float2*>((float*)out + (long)row * 512 + tid * 2) =
        make_float2(y0, y1);
  }
}

// ------------------------------------------------------------------
// Row softmax in-place on bf16 scores [T=2048 per row], z = head batch
// ------------------------------------------------------------------
__global__ __launch_bounds__(256) void softmax_rows(u16* __restrict__ S, long zStride) {
  const long base = (long)blockIdx.y * zStride + (long)blockIdx.x * 2048;
  const int tid = threadIdx.x;
  union {
    uint4 v;
    u16 h[8];
  } raw;
  raw.v = *reinterpret_cast<const uint4*>(S + base + tid * 8);
  float vals[8];
  float mx = -3e38f;
#pragma unroll
  for (int i = 0; i < 8; ++i) {
    vals[i] = bf2f(raw.h[i]);
    mx = fmaxf(mx, vals[i]);
  }
#pragma unroll
  for (int o = 32; o; o >>= 1) mx = fmaxf(mx, __shfl_xor(mx, o));
  __shared__ float sm[8];
  int wid = tid >> 6;
  if ((tid & 63) == 0) sm[wid] = mx;
  __syncthreads();
  mx = fmaxf(fmaxf(sm[0], sm[1]), fmaxf(sm[2], sm[3]));
  float sum = 0.f;
#pragma unroll
  for (int i = 0; i < 8; ++i) {
    vals[i] = __expf(vals[i] - mx);
    sum += vals[i];
  }
#pragma unroll
  for (int o = 32; o; o >>= 1) sum += __shfl_xor(sum, o);
  if ((tid & 63) == 0) sm[wid + 4] = sum;
  __syncthreads();
  sum = sm[4] + sm[5] + sm[6] + sm[7];
  const float rs = 1.f / sum;
#pragma unroll
  for (int i = 0; i < 8; ++i) raw.h[i] = f2bf(vals[i] * rs);
  *reinterpret_cast<uint4*>(S + base + tid * 8) = raw.v;
}

// ------------------------------------------------------------------
// FSMN: x[t][d] += v[t][d] + sum_j fw[d][j] * v[t+j-5][d]   (zero pad)
// v = qkv cols [1024,1536), row stride 1536
// ------------------------------------------------------------------
__global__ __launch_bounds__(256) void fsmn_add(
    float* __restrict__ x, const u16* __restrict__ qkv, const float* __restrict__ fw) {
  const int d = blockIdx.y * 256 + threadIdx.x;
  const int t = blockIdx.x;
  const u16* v = qkv + 1024 + d;
  float s = bf2f(v[(long)t * 1536]);
#pragma unroll
  for (int j = 0; j < 11; ++j) {
    int ts = t + j - 5;
    if (ts >= 0 && ts < 2048) s += fw[d * 11 + j] * bf2f(v[(long)ts * 1536]);
  }
  x[(long)t * 512 + d] += s;
}

// ------------------------------------------------------------------

extern "C" void kernel_launch(void* const* d_in, const int* in_sizes, int n_in,
                              void* d_out, int out_size, void* d_ws, size_t ws_size,
                              hipStream_t stream) {
  const float* in_x = (const float*)d_in[0];
  const float* ln1_g = (const float*)d_in[1];
  const float* ln1_b = (const float*)d_in[2];
  const float* Wqkv = (const float*)d_in[3];
  const float* bqkv = (const float*)d_in[4];
  const float* fsmn_w = (const float*)d_in[5];
  const float* Wout = (const float*)d_in[6];
  const float* bout = (const float*)d_in[7];
  const float* ln2_g = (const float*)d_in[8];
  const float* ln2_b = (const float*)d_in[9];
  const float* W1 = (const float*)d_in[10];
  const float* b1 = (const float*)d_in[11];
  const float* W2 = (const float*)d_in[12];
  const float* b2 = (const float*)d_in[13];
  const float* after_g = (const float*)d_in[14];
  const float* after_b = (const float*)d_in[15];

  const int T = 2048, D = 512, F = 2048, L = 8;
  const long TT = (long)T * T;

  char* p = (char*)d_ws;
  auto alloc = [&](size_t bytes) {
    char* r = p;
    p += (bytes + 255) & ~size_t(255);
    return r;
  };
  u16* WqkvT = (u16*)alloc(8L * 1536 * 512 * 2);
  u16* WoutT = (u16*)alloc(8L * 512 * 512 * 2);
  u16* W1T = (u16*)alloc(8L * 2048 * 512 * 2);
  u16* W2T = (u16*)alloc(8L * 512 * 2048 * 2);
  float* x = (float*)alloc((long)T * D * 4);
  u16* x1 = (u16*)alloc((long)T * D * 2);
  u16* qkv = (u16*)alloc((long)T * 1536 * 2);
  u16* vT = (u16*)alloc((long)D * T * 2);
  u16* attn = (u16*)alloc((long)T * D * 2);
  u16* hb = (u16*)alloc((long)T * F * 2);
  size_t used = (size_t)(p - (char*)d_ws);
  size_t avail = ws_size > used ? ws_size - used : 0;
  int HB = 8;
  while (HB > 1 && (size_t)HB * TT * 2 > avail) HB >>= 1;
  u16* scores = (u16*)alloc((size_t)HB * TT * 2);

  // ---- pre-pass: residual stream + bf16 transposed weights ----
  hipMemcpyAsync(x, in_x, (long)T * D * 4, hipMemcpyDeviceToDevice, stream);
  dim3 tb(32, 8);
  transpose_f32_bf16<<<dim3(1536 / 32, 512 / 32, 8), tb, 0, stream>>>(Wqkv, WqkvT, 512, 1536);
  transpose_f32_bf16<<<dim3(512 / 32, 512 / 32, 8), tb, 0, stream>>>(Wout, WoutT, 512, 512);
  transpose_f32_bf16<<<dim3(2048 / 32, 512 / 32, 8), tb, 0, stream>>>(W1, W1T, 512, 2048);
  transpose_f32_bf16<<<dim3(512 / 32, 2048 / 32, 8), tb, 0, stream>>>(W2, W2T, 2048, 512);

  for (int l = 0; l < L; ++l) {
    // LN1 -> x1 (bf16)
    layernorm_k<1><<<T, 256, 0, stream>>>(x, ln1_g + 512 * l, ln1_b + 512 * l, x1);
    // QKV: [T,512] x [512,1536] + bqkv -> qkv bf16
    gemm_bt<<<dim3(12, 16, 1), 256, 0, stream>>>(
        x1, 512, 0, WqkvT + (long)l * 1536 * 512, 512, 0, bqkv + 1536 * l,
        qkv, 0, 1536, (float*)nullptr, 0, 0, 0, T, 1536, 512, 1.f, 0);
    // vT[d][s] = v[s][d]
    transpose_bf16<<<dim3(16, 64, 1), tb, 0, stream>>>(qkv + 1024, 1536, vT, T, 512);

    for (int h0 = 0; h0 < 8; h0 += HB) {
      int hz = 8 - h0 < HB ? 8 - h0 : HB;
      // scores[h][t][s] = 0.125 * q_h[t] . k_h[s]
      gemm_bt<<<dim3(16, 16, hz), 256, 0, stream>>>(
          qkv + 64 * h0, 1536, 64, qkv + 512 + 64 * h0, 1536, 64, (const float*)nullptr,
          scores, TT, 2048, (float*)nullptr, 0, 0, 0, T, T, 64, 0.125f, 0);
      softmax_rows<<<dim3(T, hz), 256, 0, stream>>>(scores, TT);
      // attn[t][64h+d] = sum_s P[t][s] * vT[64h+d][s]
      gemm_bt<<<dim3(1, 16, hz), 256, 0, stream>>>(
          scores, 2048, TT, vT + (long)64 * T * h0, T, (long)64 * T, (const float*)nullptr,
          attn + 64 * h0, 64, 512, (float*)nullptr, 0, 0, 0, T, 64, T, 1.f, 0);
    }
    // x += attn @ Wout + bout
    gemm_bt<<<dim3(4, 16, 1), 256, 0, stream>>>(
        attn, 512, 0, WoutT + (long)l * 512 * 512, 512, 0, bout + 512 * l,
        (u16*)nullptr, 0, 0, x, 0, 512, 1, T, 512, 512, 1.f, 0);
    // x += v + depthwise_conv(v)
    fsmn_add<<<dim3(T, 2), 256, 0, stream>>>(x, qkv, fsmn_w + (long)l * 512 * 11);
    // LN2 -> x1 (bf16)
    layernorm_k<1><<<T, 256, 0, stream>>>(x, ln2_g + 512 * l, ln2_b + 512 * l, x1);
    // hb = relu(x1 @ W1 + b1)
    gemm_bt<<<dim3(16, 16, 1), 256, 0, stream>>>(
        x1, 512, 0, W1T + (long)l * 2048 * 512, 512, 0, b1 + 2048 * l,
        hb, 0, 2048, (float*)nullptr, 0, 0, 0, T, 2048, 512, 1.f, 1);
    // x += hb @ W2 + b2
    gemm_bt<<<dim3(4, 16, 1), 256, 0, stream>>>(
        hb, 2048, 0, W2T + (long)l * 512 * 2048, 2048, 0, b2 + 512 * l,
        (u16*)nullptr, 0, 0, x, 0, 512, 1, T, 512, 2048, 1.f, 0);
  }
  // final layernorm -> d_out (f32)
  layernorm_k<0><<<T, 256, 0, stream>>>(x, after_g, after_b, (float*)d_out);
}

// Round 2
// 1708.248 us; speedup vs baseline: 1.7157x; 1.7157x over previous
//
#include <hip/hip_runtime.h>

using u16 = unsigned short;
using u32 = unsigned int;

typedef __bf16 bf16x8 __attribute__((ext_vector_type(8)));
typedef float f32x4 __attribute__((ext_vector_type(4)));

__device__ __forceinline__ u16 f2bf(float f) {
  u32 u = __builtin_bit_cast(u32, f);
  u = u + 0x7FFFu + ((u >> 16) & 1u);  // round-to-nearest-even
  return (u16)(u >> 16);
}
__device__ __forceinline__ float bf2f(u16 h) {
  return __builtin_bit_cast(float, (u32)h << 16);
}

// ------------------------------------------------------------------
// transpose + f32->bf16 convert:  out[c][r] = bf16(in[r][c]) per layer z
// ------------------------------------------------------------------
__global__ __launch_bounds__(256) void transpose_f32_bf16(
    const float* __restrict__ in, u16* __restrict__ out, int R, int C) {
  __shared__ u16 tile[32][33];
  long zofs = (long)blockIdx.z * R * C;
  int c0 = blockIdx.x * 32, r0 = blockIdx.y * 32;
  for (int i = threadIdx.y; i < 32; i += 8)
    tile[i][threadIdx.x] = f2bf(in[zofs + (long)(r0 + i) * C + c0 + threadIdx.x]);
  __syncthreads();
  for (int i = threadIdx.y; i < 32; i += 8)
    out[zofs + (long)(c0 + i) * R + r0 + threadIdx.x] = tile[threadIdx.x][i];
}

// bf16 strided transpose: out[c][r] = in[r*ldin + c]
__global__ __launch_bounds__(256) void transpose_bf16(
    const u16* __restrict__ in, int ldin, u16* __restrict__ out, int R, int C) {
  __shared__ u16 tile[32][33];
  int c0 = blockIdx.x * 32, r0 = blockIdx.y * 32;
  for (int i = threadIdx.y; i < 32; i += 8)
    tile[i][threadIdx.x] = in[(long)(r0 + i) * ldin + c0 + threadIdx.x];
  __syncthreads();
  for (int i = threadIdx.y; i < 32; i += 8)
    out[(long)(c0 + i) * R + r0 + threadIdx.x] = tile[threadIdx.x][i];
}

// ------------------------------------------------------------------
// General bf16 GEMM, B transposed:  C[m][n] = sum_k A[m][k] * BT[n][k]
// 128x128 tile, BK=32, 4 waves x 4x4 frags of mfma 16x16x32 bf16.
// blockIdx.z = K-chunk (split-K); fp32 accumulate path uses atomicAdd.
// ------------------------------------------------------------------
constexpr int BM = 128, BN = 128, BK = 32, LDSP = 40;

__global__ __launch_bounds__(256) void gemm_bt(
    const u16* __restrict__ A, int lda,
    const u16* __restrict__ B, int ldb,
    const float* __restrict__ bias,
    u16* __restrict__ outBf, int ldob,
    float* __restrict__ outF, int ldof, int accF,
    int M, int N, int K, int kChunks, float scale, int relu) {
  __shared__ u16 As[BM * LDSP];
  __shared__ u16 Bs[BN * LDSP];
  const int m0 = blockIdx.y * BM, n0 = blockIdx.x * BN;
  const int tid = threadIdx.x, lane = tid & 63, wid = tid >> 6;
  const int wr = (wid >> 1) * 64, wc = (wid & 1) * 64;
  const int r16 = lane & 15, kg8 = (lane >> 4) * 8;

  f32x4 acc[4][4];
#pragma unroll
  for (int i = 0; i < 4; ++i)
#pragma unroll
    for (int j = 0; j < 4; ++j) acc[i][j] = f32x4{0.f, 0.f, 0.f, 0.f};

  const int kcs = K / kChunks;
  const int kbase = kcs * blockIdx.z;
  const int nkt = kcs / BK;
  for (int kt = 0; kt < nkt; ++kt) {
    const int k0 = kbase + kt * BK;
    __syncthreads();
#pragma unroll
    for (int c = 0; c < 2; ++c) {
      int idx = tid + c * 256;
      int row = idx >> 2, kc = (idx & 3) * 8;
      *reinterpret_cast<uint4*>(&As[row * LDSP + kc]) =
          *reinterpret_cast<const uint4*>(A + (long)(m0 + row) * lda + k0 + kc);
      *reinterpret_cast<uint4*>(&Bs[row * LDSP + kc]) =
          *reinterpret_cast<const uint4*>(B + (long)(n0 + row) * ldb + k0 + kc);
    }
    __syncthreads();

    bf16x8 af[4], bfv[4];
#pragma unroll
    for (int i = 0; i < 4; ++i)
      af[i] = *reinterpret_cast<const bf16x8*>(&As[(wr + i * 16 + r16) * LDSP + kg8]);
#pragma unroll
    for (int j = 0; j < 4; ++j)
      bfv[j] = *reinterpret_cast<const bf16x8*>(&Bs[(wc + j * 16 + r16) * LDSP + kg8]);
#pragma unroll
    for (int i = 0; i < 4; ++i)
#pragma unroll
      for (int j = 0; j < 4; ++j)
        acc[i][j] = __builtin_amdgcn_mfma_f32_16x16x32_bf16(af[i], bfv[j], acc[i][j], 0, 0, 0);
  }

  const int rg = (lane >> 4) * 4;
#pragma unroll
  for (int i = 0; i < 4; ++i) {
#pragma unroll
    for (int j = 0; j < 4; ++j) {
      int col = n0 + wc + j * 16 + r16;
      float bv = (bias && blockIdx.z == 0) ? bias[col] : 0.f;
#pragma unroll
      for (int r = 0; r < 4; ++r) {
        int row = m0 + wr + i * 16 + rg + r;
        float v = acc[i][j][r] * scale + bv;
        if (outF) {
          long idx = (long)row * ldof + col;
          if (accF) atomicAdd(&outF[idx], v);
          else outF[idx] = v;
        }
        if (outBf) {
          if (relu && v < 0.f) v = 0.f;
          outBf[(long)row * ldob + col] = f2bf(v);
        }
      }
    }
  }
}

// ------------------------------------------------------------------
// Fused flash attention. One block = (64 q-rows, 1 head). 4 waves.
// qkv: [2048][1536] bf16, head h: Q at col 64h, K at 512+64h, V at 1024+64h
// vT:  [512][2048] bf16 (v transposed), attn out: [2048][512] bf16
// ------------------------------------------------------------------
constexpr int FP = 72;  // padded 64-elem row (word stride 36 -> no >2-way conflicts)

__global__ __launch_bounds__(256) void flash_attn(
    const u16* __restrict__ qkv, const u16* __restrict__ vT,
    u16* __restrict__ attn) {
  __shared__ u16 Qs[64 * FP];
  __shared__ u16 Ks[64 * FP];
  __shared__ u16 Vs[64 * FP];      // V^T tile: [d][s]
  __shared__ u16 Ps[4][16 * FP];   // per-wave P strip
  const int h = blockIdx.y;
  const int q0 = blockIdx.x * 64;
  const int tid = threadIdx.x, lane = tid & 63, wid = tid >> 6;
  const int r16 = lane & 15, kg8 = (lane >> 4) * 8;

  {
    int row = tid >> 3, col = (tid & 7) * 8;
#pragma unroll
    for (int pp = 0; pp < 2; ++pp) {
      int r = row + pp * 32;
      *reinterpret_cast<uint4*>(&Qs[r * FP + col]) =
          *reinterpret_cast<const uint4*>(qkv + (long)(q0 + r) * 1536 + 64 * h + col);
    }
  }
  __syncthreads();
  bf16x8 qa[2];
  qa[0] = *reinterpret_cast<const bf16x8*>(&Qs[(wid * 16 + r16) * FP + kg8]);
  qa[1] = *reinterpret_cast<const bf16x8*>(&Qs[(wid * 16 + r16) * FP + 32 + kg8]);

  f32x4 oacc[4];
#pragma unroll
  for (int j = 0; j < 4; ++j) oacc[j] = f32x4{0.f, 0.f, 0.f, 0.f};
  float m[4], l[4];
#pragma unroll
  for (int r = 0; r < 4; ++r) { m[r] = -3e38f; l[r] = 0.f; }

  for (int kt = 0; kt < 32; ++kt) {
    __syncthreads();
    {
      int row = tid >> 3, col = (tid & 7) * 8;
#pragma unroll
      for (int pp = 0; pp < 2; ++pp) {
        int r = row + pp * 32;
        *reinterpret_cast<uint4*>(&Ks[r * FP + col]) =
            *reinterpret_cast<const uint4*>(qkv + (long)(kt * 64 + r) * 1536 + 512 + 64 * h + col);
        *reinterpret_cast<uint4*>(&Vs[r * FP + col]) =
            *reinterpret_cast<const uint4*>(vT + (long)(64 * h + r) * 2048 + kt * 64 + col);
      }
    }
    __syncthreads();

    // S = Q K^T  (wave's 16 q-rows x 64 k-rows)
    f32x4 sacc[4];
#pragma unroll
    for (int j = 0; j < 4; ++j) sacc[j] = f32x4{0.f, 0.f, 0.f, 0.f};
#pragma unroll
    for (int j = 0; j < 4; ++j) {
      bf16x8 b0 = *reinterpret_cast<const bf16x8*>(&Ks[(j * 16 + r16) * FP + kg8]);
      bf16x8 b1 = *reinterpret_cast<const bf16x8*>(&Ks[(j * 16 + r16) * FP + 32 + kg8]);
      sacc[j] = __builtin_amdgcn_mfma_f32_16x16x32_bf16(qa[0], b0, sacc[j], 0, 0, 0);
      sacc[j] = __builtin_amdgcn_mfma_f32_16x16x32_bf16(qa[1], b1, sacc[j], 0, 0, 0);
    }

    // online softmax over the wave's 16 rows (each lane: 4 rows, 4 cols each)
#pragma unroll
    for (int r = 0; r < 4; ++r) {
      float s0 = sacc[0][r] * 0.125f, s1 = sacc[1][r] * 0.125f;
      float s2 = sacc[2][r] * 0.125f, s3 = sacc[3][r] * 0.125f;
      float rm = fmaxf(fmaxf(s0, s1), fmaxf(s2, s3));
#pragma unroll
      for (int o = 1; o < 16; o <<= 1) rm = fmaxf(rm, __shfl_xor(rm, o));
      float mn = fmaxf(m[r], rm);
      float alpha = __expf(m[r] - mn);
      m[r] = mn;
      float e0 = __expf(s0 - mn), e1 = __expf(s1 - mn);
      float e2 = __expf(s2 - mn), e3 = __expf(s3 - mn);
      float rs = (e0 + e1) + (e2 + e3);
#pragma unroll
      for (int o = 1; o < 16; o <<= 1) rs += __shfl_xor(rs, o);
      l[r] = l[r] * alpha + rs;
      oacc[0][r] *= alpha;
      oacc[1][r] *= alpha;
      oacc[2][r] *= alpha;
      oacc[3][r] *= alpha;
      int prow = (lane >> 4) * 4 + r;
      Ps[wid][prow * FP + 0 + r16] = f2bf(e0);
      Ps[wid][prow * FP + 16 + r16] = f2bf(e1);
      Ps[wid][prow * FP + 32 + r16] = f2bf(e2);
      Ps[wid][prow * FP + 48 + r16] = f2bf(e3);
    }

    // O += P V   (A = wave's P strip, B = V^T tile)
#pragma unroll
    for (int st = 0; st < 2; ++st) {
      bf16x8 pa = *reinterpret_cast<const bf16x8*>(&Ps[wid][r16 * FP + st * 32 + kg8]);
#pragma unroll
      for (int j = 0; j < 4; ++j) {
        bf16x8 bv = *reinterpret_cast<const bf16x8*>(&Vs[(j * 16 + r16) * FP + st * 32 + kg8]);
        oacc[j] = __builtin_amdgcn_mfma_f32_16x16x32_bf16(pa, bv, oacc[j], 0, 0, 0);
      }
    }
  }

  const int rg = (lane >> 4) * 4;
#pragma unroll
  for (int j = 0; j < 4; ++j) {
#pragma unroll
    for (int r = 0; r < 4; ++r) {
      float v = oacc[j][r] / l[r];
      attn[(long)(q0 + wid * 16 + rg + r) * 512 + 64 * h + j * 16 + r16] = f2bf(v);
    }
  }
}

// ------------------------------------------------------------------
// LayerNorm over D=512, one block per row.
// ------------------------------------------------------------------
__device__ __forceinline__ void block_reduce2(float& s, float& ss) {
#pragma unroll
  for (int o = 32; o; o >>= 1) {
    s += __shfl_xor(s, o);
    ss += __shfl_xor(ss, o);
  }
  __shared__ float sm[8];
  int wid = threadIdx.x >> 6;
  if ((threadIdx.x & 63) == 0) {
    sm[wid] = s;
    sm[wid + 4] = ss;
  }
  __syncthreads();
  s = sm[0] + sm[1] + sm[2] + sm[3];
  ss = sm[4] + sm[5] + sm[6] + sm[7];
}

template <int OUTBF>
__global__ __launch_bounds__(256) void layernorm_k(
    const float* __restrict__ xin, const float* __restrict__ g,
    const float* __restrict__ bta, void* __restrict__ out) {
  const int row = blockIdx.x, tid = threadIdx.x;
  const float2 v = *reinterpret_cast<const float2*>(xin + (long)row * 512 + tid * 2);
  float s = v.x + v.y, ss = v.x * v.x + v.y * v.y;
  block_reduce2(s, ss);
  const float mean = s * (1.f / 512.f);
  const float var = ss * (1.f / 512.f) - mean * mean;
  const float inv = rsqrtf(var + 1e-5f);
  const float2 gg = *reinterpret_cast<const float2*>(g + tid * 2);
  const float2 bb = *reinterpret_cast<const float2*>(bta + tid * 2);
  const float y0 = (v.x - mean) * inv * gg.x + bb.x;
  const float y1 = (v.y - mean) * inv * gg.y + bb.y;
  if (OUTBF) {
    u16* o = (u16*)out + (long)row * 512 + tid * 2;
    o[0] = f2bf(y0);
    o[1] = f2bf(y1);
  } else {
    *reinterpret_cast<float2*>((float*)out + (long)row * 512 + tid * 2) =
        make_float2(y0, y1);
  }
}

// ------------------------------------------------------------------
// FSMN: x[t][d] += v[t][d] + sum_j fw[d][j] * v[t+j-5][d]   (zero pad)
// ------------------------------------------------------------------
__global__ __launch_bounds__(256) void fsmn_add(
    float* __restrict__ x, const u16* __restrict__ qkv, const float* __restrict__ fw) {
  const int d = blockIdx.y * 256 + threadIdx.x;
  const int t = blockIdx.x;
  const u16* v = qkv + 1024 + d;
  float s = bf2f(v[(long)t * 1536]);
#pragma unroll
  for (int j = 0; j < 11; ++j) {
    int ts = t + j - 5;
    if (ts >= 0 && ts < 2048) s += fw[d * 11 + j] * bf2f(v[(long)ts * 1536]);
  }
  x[(long)t * 512 + d] += s;
}

// ------------------------------------------------------------------

extern "C" void kernel_launch(void* const* d_in, const int* in_sizes, int n_in,
                              void* d_out, int out_size, void* d_ws, size_t ws_size,
                              hipStream_t stream) {
  const float* in_x = (const float*)d_in[0];
  const float* ln1_g = (const float*)d_in[1];
  const float* ln1_b = (const float*)d_in[2];
  const float* Wqkv = (const float*)d_in[3];
  const float* bqkv = (const float*)d_in[4];
  const float* fsmn_w = (const float*)d_in[5];
  const float* Wout = (const float*)d_in[6];
  const float* bout = (const float*)d_in[7];
  const float* ln2_g = (const float*)d_in[8];
  const float* ln2_b = (const float*)d_in[9];
  const float* W1 = (const float*)d_in[10];
  const float* b1 = (const float*)d_in[11];
  const float* W2 = (const float*)d_in[12];
  const float* b2 = (const float*)d_in[13];
  const float* after_g = (const float*)d_in[14];
  const float* after_b = (const float*)d_in[15];

  const int T = 2048, D = 512, F = 2048, L = 8;

  char* p = (char*)d_ws;
  auto alloc = [&](size_t bytes) {
    char* r = p;
    p += (bytes + 255) & ~size_t(255);
    return r;
  };
  u16* WqkvT = (u16*)alloc(8L * 1536 * 512 * 2);
  u16* WoutT = (u16*)alloc(8L * 512 * 512 * 2);
  u16* W1T = (u16*)alloc(8L * 2048 * 512 * 2);
  u16* W2T = (u16*)alloc(8L * 512 * 2048 * 2);
  float* x = (float*)alloc((long)T * D * 4);
  u16* x1 = (u16*)alloc((long)T * D * 2);
  u16* qkv = (u16*)alloc((long)T * 1536 * 2);
  u16* vT = (u16*)alloc((long)D * T * 2);
  u16* attn = (u16*)alloc((long)T * D * 2);
  u16* hb = (u16*)alloc((long)T * F * 2);

  // ---- pre-pass: residual stream + bf16 transposed weights ----
  hipMemcpyAsync(x, in_x, (long)T * D * 4, hipMemcpyDeviceToDevice, stream);
  dim3 tb(32, 8);
  transpose_f32_bf16<<<dim3(1536 / 32, 512 / 32, 8), tb, 0, stream>>>(Wqkv, WqkvT, 512, 1536);
  transpose_f32_bf16<<<dim3(512 / 32, 512 / 32, 8), tb, 0, stream>>>(Wout, WoutT, 512, 512);
  transpose_f32_bf16<<<dim3(2048 / 32, 512 / 32, 8), tb, 0, stream>>>(W1, W1T, 512, 2048);
  transpose_f32_bf16<<<dim3(512 / 32, 2048 / 32, 8), tb, 0, stream>>>(W2, W2T, 2048, 512);

  for (int l = 0; l < L; ++l) {
    layernorm_k<1><<<T, 256, 0, stream>>>(x, ln1_g + 512 * l, ln1_b + 512 * l, x1);
    // QKV: [T,512] x [512,1536] + bqkv -> qkv bf16
    gemm_bt<<<dim3(12, 16, 1), 256, 0, stream>>>(
        x1, 512, WqkvT + (long)l * 1536 * 512, 512, bqkv + 1536 * l,
        qkv, 1536, (float*)nullptr, 0, 0, T, 1536, 512, 1, 1.f, 0);
    // vT[d][s] = v[s][d]
    transpose_bf16<<<dim3(16, 64, 1), tb, 0, stream>>>(qkv + 1024, 1536, vT, T, 512);
    // fused attention -> attn
    flash_attn<<<dim3(32, 8, 1), 256, 0, stream>>>(qkv, vT, attn);
    // x += attn @ Wout + bout   (split-K = 4)
    gemm_bt<<<dim3(4, 16, 4), 256, 0, stream>>>(
        attn, 512, WoutT + (long)l * 512 * 512, 512, bout + 512 * l,
        (u16*)nullptr, 0, x, 512, 1, T, 512, 512, 4, 1.f, 0);
    // x += v + depthwise_conv(v)
    fsmn_add<<<dim3(T, 2), 256, 0, stream>>>(x, qkv, fsmn_w + (long)l * 512 * 11);
    layernorm_k<1><<<T, 256, 0, stream>>>(x, ln2_g + 512 * l, ln2_b + 512 * l, x1);
    // hb = relu(x1 @ W1 + b1)
    gemm_bt<<<dim3(16, 16, 1), 256, 0, stream>>>(
        x1, 512, W1T + (long)l * 2048 * 512, 512, b1 + 2048 * l,
        hb, 2048, (float*)nullptr, 0, 0, T, 2048, 512, 1, 1.f, 1);
    // x += hb @ W2 + b2   (split-K = 4)
    gemm_bt<<<dim3(4, 16, 4), 256, 0, stream>>>(
        hb, 2048, W2T + (long)l * 512 * 2048, 2048, b2 + 512 * l,
        (u16*)nullptr, 0, x, 512, 1, T, 512, 2048, 4, 1.f, 0);
  }
  layernorm_k<0><<<T, 256, 0, stream>>>(x, after_g, after_b, (float*)d_out);
}